// Round 4
// baseline (1084.353 us; speedup 1.0000x reference)
//
#include <hip/hip_runtime.h>
#include <math.h>

// Max-plus DP: out[b,t,k] = x[b,t,k] + max(out[b,t-1,k], out[b,t-1,k-1])
// 32 batches x 8 column groups = 256 blocks, 1 wave each, 2 cols/lane.
//
// ROOT CAUSE FOUND (round 3 counters): with a 32-row float2 prefetch ring
// (64 regs), the allocator placed the ring in AGPRs (VGPR_Count=40/44 —
// too small to hold it). global_load can't write AGPRs, so every row was
// load -> waitcnt(just-issued load) -> v_accvgpr_write: one fully exposed
// memory latency (~550cy) per row, VALUBusy ~1%. All prior perf deltas
// (bytes/row scaling, round-3 regression) are explained by this.
//
// Fix: PD=16 ring (32 VGPRs) that fits in architectural VGPRs. Loads then
// land directly in their destination registers and the consumer row waits
// with ~16 rows of vmcnt slack. No sched_barrier(0): the scheduler must be
// free to place loads in the slack window. Row cost target:
// max(~30cy ALU, 2 VMEM * ~900cy / 32 outstanding ~= 56cy).
//
// Cross-block protocol (relaxed agent atomics + vmcnt(0) drain + lag-2
// flags) is unchanged from the verified kernel. Boundary broadcast uses
// readlane (VALU); the shfl_up is issued one row early.

#define BB 32
#define TT 2048
#define KK 1024
#define GG 8
#define WW (KK / GG)      // 128 cols per group
#define RR 32             // rows per tile (flag granularity)
#define PD 16             // prefetch ring depth (32 VGPRs)
#define NT (TT / RR)      // 64 tiles

__global__ __launch_bounds__(64, 1)
void harddtw_vring(const float* __restrict__ x, float* __restrict__ out,
                   int* __restrict__ flags)
{
    const int bid  = blockIdx.x;
    const int g    = bid >> 5;   // column group 0..7
    const int b    = bid & 31;   // batch
    const int lane = threadIdx.x;
    const bool lz  = (lane == 0);

    const int k0 = g * WW;
    const int kc = k0 + (lane << 1);
    const size_t base = (size_t)b * TT * KK;

    const float* xl = x + base + kc;           // this lane's x column pair
    float*       ol = out + base + kc;         // out cursor (row 0)
    const float* bb = out + base + (k0 - 1);   // boundary column (g>0 only)

    int* myflag = flags + bid;
    int* upflag = flags + bid - 32;            // same batch, group g-1

    // --- PD-slot prefetch ring, architectural VGPRs. Row i uses slot i&15;
    // after consuming, the same slot receives row i+16. ---
    float2 ring[PD];
#pragma unroll
    for (int j = 0; j < PD; ++j)
        ring[j] = *(const float2*)(xl + (size_t)j * KK);
    const float* xpre = xl + (size_t)PD * KK;  // next x row to prefetch

    float pv0 = 0.0f, pv1 = 0.0f;              // prev-row values (0 => row0 = x)
    float sh_prev = 0.0f;                      // left-neighbor pv1 from "row -1"
    float bcur = -INFINITY, bnxt = -INFINITY;  // boundary vals, lane j = row j-1 of tile

    if (g > 0) {
        // tile 0 boundary: rows -1..30 of column k0-1
        while (__hip_atomic_load(upflag, __ATOMIC_RELAXED,
                                 __HIP_MEMORY_SCOPE_AGENT) < 1)
            __builtin_amdgcn_s_sleep(1);
        __asm__ volatile("" ::: "memory");
        if (lane == 0) {
            bcur = 0.0f;                       // row -1 virtual: max(0,0)
        } else if (lane < RR) {
            bcur = __hip_atomic_load(bb + (size_t)(lane - 1) * KK,
                                     __ATOMIC_RELAXED, __HIP_MEMORY_SCOPE_AGENT);
        }
    }

#pragma unroll 1
    for (int r = 0; r < NT; ++r) {
        // Lag-2: require producer 2 tiles ahead, then issue next tile's
        // boundary loads now so their latency hides behind this tile.
        if (g > 0 && r < NT - 1) {
            while (__hip_atomic_load(upflag, __ATOMIC_RELAXED,
                                     __HIP_MEMORY_SCOPE_AGENT) < r + 2)
                __builtin_amdgcn_s_sleep(1);
            __asm__ volatile("" ::: "memory");
            if (lane < RR)
                bnxt = __hip_atomic_load(
                    bb + (size_t)((r + 1) * RR + lane - 1) * KK,
                    __ATOMIC_RELAXED, __HIP_MEMORY_SCOPE_AGENT);
        }

        const bool pub  = (g < GG - 1);
        const bool last = (r == NT - 1);

#pragma unroll
        for (int j = 0; j < RR; ++j) {
            float2 xv = ring[j & (PD - 1)];
            // Boundary for this row: uniform readlane (VALU/SALU, no DS).
            float bv = __int_as_float(
                __builtin_amdgcn_readlane(__float_as_int(bcur), j));
            float left = lz ? bv : sh_prev;    // sh_prev = prev row's shfl
            float n0 = xv.x + fmaxf(pv0, left);
            float n1 = xv.y + fmaxf(pv1, pv0);
            float sh_new = __shfl_up(n1, 1);   // consumed next row

            float2 o; o.x = n0; o.y = n1;
            if (pub && lane == 63) {
                // Consumer reads our boundary pair via agent atomics only.
                union { float2 f; unsigned long long u; } cv; cv.f = o;
                __hip_atomic_store((unsigned long long*)ol, cv.u,
                                   __ATOMIC_RELAXED, __HIP_MEMORY_SCOPE_AGENT);
            } else {
                *(float2*)ol = o;
            }
            ol += KK;

            if (!last || j < RR - PD) {        // prefetch row (r*RR+j+PD)
                ring[j & (PD - 1)] = *(const float2*)xpre;
                xpre += KK;
            }

            pv0 = n0; pv1 = n1; sh_prev = sh_new;
        }

        bcur = bnxt;

        if (pub) {
            // Drain our stores to the coherence point, then publish.
            __asm__ volatile("s_waitcnt vmcnt(0)" ::: "memory");
            if (lane == 0)
                __hip_atomic_store(myflag, r + 1, __ATOMIC_RELAXED,
                                   __HIP_MEMORY_SCOPE_AGENT);
        }
    }
}

extern "C" void kernel_launch(void* const* d_in, const int* in_sizes, int n_in,
                              void* d_out, int out_size, void* d_ws, size_t ws_size,
                              hipStream_t stream) {
    (void)in_sizes; (void)n_in; (void)out_size; (void)ws_size;
    const float* x = (const float*)d_in[0];
    float* out = (float*)d_out;
    int* flags = (int*)d_ws;

    // ws is re-poisoned to 0xAA before every timed launch; flags must be 0.
    hipMemsetAsync(flags, 0, BB * GG * sizeof(int), stream);

    harddtw_vring<<<dim3(BB * GG), dim3(64), 0, stream>>>(x, out, flags);
}

// Round 5
// 612.075 us; speedup vs baseline: 1.7716x; 1.7716x over previous
//
#include <hip/hip_runtime.h>
#include <math.h>

// Max-plus DP: out[b,t,k] = x[b,t,k] + max(out[b,t-1,k], out[b,t-1,k-1])
// 32 batches x 8 column groups = 256 blocks, 1 wave each, 2 cols/lane.
//
// Rounds 1-4 post-mortem: per-row cost pinned at ~550cy across three
// different register-prefetch structures (VGPR_Count 44/104/40/28 shows the
// ring never landed in architectural VGPRs). The two per-row serializer
// candidates that were NEVER changed: (a) lane-63 agent-scope store to the
// IF$ coherence point every row, (b) global->reg prefetch defeated by
// AGPR placement / load sinking (one exposed VMEM latency per row).
// This version removes both structurally:
//   - x is staged tile-ahead into double-buffered LDS via
//     global_load_lds (no dest VGPR: nothing to misplace or sink);
//     per-row consume is ds_read_b64, prefetched 8 rows deep (16 VGPRs).
//   - boundary column goes through a compact per-group workspace array
//     (bws[b][g][t]): lane63 stages n1 into LDS scratch each row; ONCE per
//     tile lanes 0-31 do one coalesced 128B agent-scope store. out is
//     never read cross-block; all out-stores are plain.
// Flag protocol (relaxed agent atomics, lag-2, vmcnt(0) release drain)
// unchanged. The drain also serves as the staging fence.

#define BB 32
#define TT 2048
#define KK 1024
#define GG 8
#define WW (KK / GG)      // 128 cols per group
#define RR 32             // rows per tile (flag granularity)
#define NT (TT / RR)      // 64 tiles
#define PD 8              // ds_read prefetch depth (16 VGPRs)

typedef __attribute__((address_space(1))) void GV;  // global
typedef __attribute__((address_space(3))) void LV;  // LDS

__global__ __launch_bounds__(64, 1)
void harddtw_lds(const float* __restrict__ x, float* __restrict__ out,
                 int* __restrict__ flags, float* __restrict__ bws)
{
    const int bid  = blockIdx.x;
    const int g    = bid >> 5;   // column group 0..7
    const int b    = bid & 31;   // batch
    const int lane = threadIdx.x;
    const bool lz  = (lane == 0);

    const int k0 = g * WW;
    const int kc = k0 + (lane << 1);
    const size_t base = (size_t)b * TT * KK;

    float* ol = out + base + kc;               // out cursor (row 0)

    int* myflag = flags + bid;
    int* upflag = flags + bid - 32;            // same batch, group g-1
    float*       mybw = bws + ((size_t)(b * GG + g)) * TT;       // we publish
    const float* upbw = bws + ((size_t)(b * GG + g - 1)) * TT;   // we consume

    __shared__ float lds[2][RR * WW];          // 2 x 16KB x-tile buffers
    __shared__ float bsc[RR];                  // lane63 boundary scratch

    // Staging: inst i stages rows 2i,2i+1 (1KB linear LDS; dest is
    // wave-uniform base + lane*16). Lane l covers row 2i+(l>>5),
    // float cols [4*(l&31), +4).
    const float* xstage = x + base + k0 + (size_t)(lane >> 5) * KK
                          + ((lane & 31) << 2);

    // Stage tile 0 into buffer 0 (latency overlaps the flag wait below).
    {
        const float* gp = xstage;
#pragma unroll
        for (int i = 0; i < RR / 2; ++i) {
            __builtin_amdgcn_global_load_lds((GV*)(void*)gp,
                                             (LV*)(void*)&lds[0][i * 256],
                                             16, 0, 0);
            gp += 2 * KK;
        }
    }

    float pv0 = 0.0f, pv1 = 0.0f;              // prev-row values (0 => row0 = x)
    float sh_prev = 0.0f;                      // left-neighbor pv1 from "row -1"
    float bcur = -INFINITY, bnxt = -INFINITY;  // boundary, lane j = row j-1 of tile

    if (g > 0) {
        while (__hip_atomic_load(upflag, __ATOMIC_RELAXED,
                                 __HIP_MEMORY_SCOPE_AGENT) < 1)
            __builtin_amdgcn_s_sleep(1);
        __asm__ volatile("" ::: "memory");
        if (lane == 0) {
            bcur = 0.0f;                       // row -1 virtual: max(0,0)
        } else if (lane < RR) {
            bcur = __hip_atomic_load(upbw + lane - 1, __ATOMIC_RELAXED,
                                     __HIP_MEMORY_SCOPE_AGENT);
        }
    }

    __asm__ volatile("s_waitcnt vmcnt(0)" ::: "memory");  // tile 0 staged

    float2 rb[PD];
    int buf = 0;
#pragma unroll
    for (int p = 0; p < PD; ++p)
        rb[p] = *(const float2*)&lds[0][p * WW + (lane << 1)];

#pragma unroll 1
    for (int r = 0; r < NT; ++r) {
        // Lag-2: producer must be 2 tiles ahead; then issue next tile's
        // boundary loads (coalesced 32 floats) so latency hides here.
        if (g > 0 && r < NT - 1) {
            while (__hip_atomic_load(upflag, __ATOMIC_RELAXED,
                                     __HIP_MEMORY_SCOPE_AGENT) < r + 2)
                __builtin_amdgcn_s_sleep(1);
            __asm__ volatile("" ::: "memory");
            if (lane < RR)
                bnxt = __hip_atomic_load(
                    upbw + (size_t)(r + 1) * RR + lane - 1,
                    __ATOMIC_RELAXED, __HIP_MEMORY_SCOPE_AGENT);
        }

        // Stage tile r+1 into the other buffer; completes by the tile-end
        // drain (one tile of slack).
        if (r < NT - 1) {
            const float* gp = xstage + (size_t)(r + 1) * RR * KK;
            float* lp = &lds[buf ^ 1][0];
#pragma unroll
            for (int i = 0; i < RR / 2; ++i) {
                __builtin_amdgcn_global_load_lds((GV*)(void*)gp,
                                                 (LV*)(void*)(lp + i * 256),
                                                 16, 0, 0);
                gp += 2 * KK;
            }
        }

        const bool pub = (g < GG - 1);

#pragma unroll
        for (int j = 0; j < RR; ++j) {
            float2 xv = rb[j & (PD - 1)];
            // Boundary broadcast: uniform readlane (VALU, no DS).
            float bv = __int_as_float(
                __builtin_amdgcn_readlane(__float_as_int(bcur), j));
            float left = lz ? bv : sh_prev;    // sh_prev = prev row's shfl
            float n0 = xv.x + fmaxf(pv0, left);
            float n1 = xv.y + fmaxf(pv1, pv0);
            float sh_new = __shfl_up(n1, 1);   // consumed next row

            float2 o; o.x = n0; o.y = n1;
            *(float2*)ol = o;                  // plain store; never read x-block
            ol += KK;
            if (lane == 63) bsc[j] = n1;       // stage boundary value in LDS

            if (j < RR - PD)                   // ds prefetch, 8 rows ahead
                rb[j & (PD - 1)] =
                    *(const float2*)&lds[buf][(j + PD) * WW + (lane << 1)];

            pv0 = n0; pv1 = n1; sh_prev = sh_new;
            __builtin_amdgcn_sched_barrier(0); // pin the row pipeline
        }

        bcur = bnxt;

        // Batched boundary publish: one coalesced 128B agent store per tile.
        __asm__ volatile("s_waitcnt lgkmcnt(0)" ::: "memory"); // bsc visible
        if (pub && lane < RR)
            __hip_atomic_store(mybw + (size_t)r * RR + lane, bsc[lane],
                               __ATOMIC_RELAXED, __HIP_MEMORY_SCOPE_AGENT);
        // Release drain: boundary store + out stores + next-tile staging.
        __asm__ volatile("s_waitcnt vmcnt(0)" ::: "memory");
        if (pub && lz)
            __hip_atomic_store(myflag, r + 1, __ATOMIC_RELAXED,
                               __HIP_MEMORY_SCOPE_AGENT);

        if (r < NT - 1) {
            buf ^= 1;
#pragma unroll
            for (int p = 0; p < PD; ++p)       // preload next tile's rows 0..7
                rb[p] = *(const float2*)&lds[buf][p * WW + (lane << 1)];
        }
    }
}

extern "C" void kernel_launch(void* const* d_in, const int* in_sizes, int n_in,
                              void* d_out, int out_size, void* d_ws, size_t ws_size,
                              hipStream_t stream) {
    (void)in_sizes; (void)n_in; (void)out_size; (void)ws_size;
    const float* x = (const float*)d_in[0];
    float* out = (float*)d_out;
    int* flags = (int*)d_ws;
    float* bws = (float*)((char*)d_ws + 4096);  // [BB][GG][TT] floats = 2MB

    // ws is re-poisoned to 0xAA before every timed launch; flags must be 0.
    // bws needs no init: every read is flag-gated behind its producer.
    hipMemsetAsync(flags, 0, BB * GG * sizeof(int), stream);

    harddtw_lds<<<dim3(BB * GG), dim3(64), 0, stream>>>(x, out, flags, bws);
}

// Round 6
// 605.708 us; speedup vs baseline: 1.7902x; 1.0105x over previous
//
#include <hip/hip_runtime.h>
#include <math.h>

// Max-plus DP: out[b,t,k] = x[b,t,k] + max(out[b,t-1,k], out[b,t-1,k-1])
// 32 batches x 8 column groups = 256 blocks, 1 wave each, 2 cols/lane.
//
// Round-5 structure (307us/dispatch, passed): x staged tile-ahead into
// double-buffered LDS via global_load_lds; per-row consume is ds_read_b64
// prefetched 8 rows deep; boundary goes through compact bws[b][g][t] with
// one coalesced agent-scope publish per tile; lag-2 flag protocol.
//
// Round-6 change (ONE variable): the per-row sched_barrier(0) is removed
// and the row body reordered. Rationale: counters showed ~295cy/row at
// VALUBusy 3.2% — the barrier forced each row to expose the full DS
// latency of the previous row's shfl_up. The dependency cycle through the
// shfl spans TWO rows (n1_j -> shfl -> n0_{j+1} -> n1_{j+2}; the n1 chain
// is shfl-free), so an unpinned schedule can amortize DS latency across
// rows: target ~65cy/row. Row body order now: n1 (shfl-free) first, shfl
// issued immediately, prev-row shfl consumed last (n0).

#define BB 32
#define TT 2048
#define KK 1024
#define GG 8
#define WW (KK / GG)      // 128 cols per group
#define RR 32             // rows per tile (flag granularity)
#define NT (TT / RR)      // 64 tiles
#define PD 8              // ds_read prefetch depth (16 VGPRs)

typedef __attribute__((address_space(1))) void GV;  // global
typedef __attribute__((address_space(3))) void LV;  // LDS

__global__ __launch_bounds__(64, 1)
void harddtw_pipe6(const float* __restrict__ x, float* __restrict__ out,
                   int* __restrict__ flags, float* __restrict__ bws)
{
    const int bid  = blockIdx.x;
    const int g    = bid >> 5;   // column group 0..7
    const int b    = bid & 31;   // batch
    const int lane = threadIdx.x;
    const bool lz  = (lane == 0);

    const int k0 = g * WW;
    const int kc = k0 + (lane << 1);
    const size_t base = (size_t)b * TT * KK;

    float* ol = out + base + kc;               // out cursor (row 0)

    int* myflag = flags + bid;
    int* upflag = flags + bid - 32;            // same batch, group g-1
    float*       mybw = bws + ((size_t)(b * GG + g)) * TT;       // we publish
    const float* upbw = bws + ((size_t)(b * GG + g - 1)) * TT;   // we consume

    __shared__ float lds[2][RR * WW];          // 2 x 16KB x-tile buffers
    __shared__ float bsc[RR];                  // lane63 boundary scratch

    // Staging: inst i stages rows 2i,2i+1 (1KB linear LDS; dest is
    // wave-uniform base + lane*16). Lane l covers row 2i+(l>>5),
    // float cols [4*(l&31), +4).
    const float* xstage = x + base + k0 + (size_t)(lane >> 5) * KK
                          + ((lane & 31) << 2);

    // Stage tile 0 into buffer 0 (latency overlaps the flag wait below).
    {
        const float* gp = xstage;
#pragma unroll
        for (int i = 0; i < RR / 2; ++i) {
            __builtin_amdgcn_global_load_lds((GV*)(void*)gp,
                                             (LV*)(void*)&lds[0][i * 256],
                                             16, 0, 0);
            gp += 2 * KK;
        }
    }

    float pv0 = 0.0f, pv1 = 0.0f;              // prev-row values (0 => row0 = x)
    float sh_prev = 0.0f;                      // left-neighbor pv1 from "row -1"
    float bcur = -INFINITY, bnxt = -INFINITY;  // boundary, lane j = row j-1 of tile

    if (g > 0) {
        while (__hip_atomic_load(upflag, __ATOMIC_RELAXED,
                                 __HIP_MEMORY_SCOPE_AGENT) < 1)
            __builtin_amdgcn_s_sleep(1);
        __asm__ volatile("" ::: "memory");
        if (lane == 0) {
            bcur = 0.0f;                       // row -1 virtual: max(0,0)
        } else if (lane < RR) {
            bcur = __hip_atomic_load(upbw + lane - 1, __ATOMIC_RELAXED,
                                     __HIP_MEMORY_SCOPE_AGENT);
        }
    }

    __asm__ volatile("s_waitcnt vmcnt(0)" ::: "memory");  // tile 0 staged

    float2 rb[PD];
    int buf = 0;
#pragma unroll
    for (int p = 0; p < PD; ++p)
        rb[p] = *(const float2*)&lds[0][p * WW + (lane << 1)];

#pragma unroll 1
    for (int r = 0; r < NT; ++r) {
        // Lag-2: producer must be 2 tiles ahead; then issue next tile's
        // boundary loads (coalesced 32 floats) so latency hides here.
        if (g > 0 && r < NT - 1) {
            while (__hip_atomic_load(upflag, __ATOMIC_RELAXED,
                                     __HIP_MEMORY_SCOPE_AGENT) < r + 2)
                __builtin_amdgcn_s_sleep(1);
            __asm__ volatile("" ::: "memory");
            if (lane < RR)
                bnxt = __hip_atomic_load(
                    upbw + (size_t)(r + 1) * RR + lane - 1,
                    __ATOMIC_RELAXED, __HIP_MEMORY_SCOPE_AGENT);
        }

        // Stage tile r+1 into the other buffer; completes by the tile-end
        // drain (one tile of slack).
        if (r < NT - 1) {
            const float* gp = xstage + (size_t)(r + 1) * RR * KK;
            float* lp = &lds[buf ^ 1][0];
#pragma unroll
            for (int i = 0; i < RR / 2; ++i) {
                __builtin_amdgcn_global_load_lds((GV*)(void*)gp,
                                                 (LV*)(void*)(lp + i * 256),
                                                 16, 0, 0);
                gp += 2 * KK;
            }
        }

        const bool pub = (g < GG - 1);

#pragma unroll
        for (int j = 0; j < RR; ++j) {
            float2 xv = rb[j & (PD - 1)];
            // Shfl-free chain first; issue this row's shfl ASAP.
            float n1 = xv.y + fmaxf(pv1, pv0);
            float sh_new = __shfl_up(n1, 1);   // consumed next row
            // Boundary broadcast: uniform readlane (VALU, no DS).
            float bv = __int_as_float(
                __builtin_amdgcn_readlane(__float_as_int(bcur), j));
            float left = lz ? bv : sh_prev;    // prev row's shfl, consumed late
            float n0 = xv.x + fmaxf(pv0, left);

            float2 o; o.x = n0; o.y = n1;
            *(float2*)ol = o;                  // plain store; never read x-block
            ol += KK;
            if (lane == 63) bsc[j] = n1;       // stage boundary value in LDS

            if (j < RR - PD)                   // ds prefetch, 8 rows ahead
                rb[j & (PD - 1)] =
                    *(const float2*)&lds[buf][(j + PD) * WW + (lane << 1)];

            pv0 = n0; pv1 = n1; sh_prev = sh_new;
        }

        bcur = bnxt;

        // Batched boundary publish: one coalesced 128B agent store per tile.
        __asm__ volatile("s_waitcnt lgkmcnt(0)" ::: "memory"); // bsc visible
        if (pub && lane < RR)
            __hip_atomic_store(mybw + (size_t)r * RR + lane, bsc[lane],
                               __ATOMIC_RELAXED, __HIP_MEMORY_SCOPE_AGENT);
        // Release drain: boundary store + out stores + next-tile staging.
        __asm__ volatile("s_waitcnt vmcnt(0)" ::: "memory");
        if (pub && lz)
            __hip_atomic_store(myflag, r + 1, __ATOMIC_RELAXED,
                               __HIP_MEMORY_SCOPE_AGENT);

        if (r < NT - 1) {
            buf ^= 1;
#pragma unroll
            for (int p = 0; p < PD; ++p)       // preload next tile's rows 0..7
                rb[p] = *(const float2*)&lds[buf][p * WW + (lane << 1)];
        }
    }
}

extern "C" void kernel_launch(void* const* d_in, const int* in_sizes, int n_in,
                              void* d_out, int out_size, void* d_ws, size_t ws_size,
                              hipStream_t stream) {
    (void)in_sizes; (void)n_in; (void)out_size; (void)ws_size;
    const float* x = (const float*)d_in[0];
    float* out = (float*)d_out;
    int* flags = (int*)d_ws;
    float* bws = (float*)((char*)d_ws + 4096);  // [BB][GG][TT] floats = 2MB

    // ws is re-poisoned to 0xAA before every timed launch; flags must be 0.
    // bws needs no init: every read is flag-gated behind its producer.
    hipMemsetAsync(flags, 0, BB * GG * sizeof(int), stream);

    harddtw_pipe6<<<dim3(BB * GG), dim3(64), 0, stream>>>(x, out, flags, bws);
}

// Round 7
// 598.320 us; speedup vs baseline: 1.8123x; 1.0123x over previous
//
#include <hip/hip_runtime.h>
#include <math.h>

// Max-plus DP: out[b,t,k] = x[b,t,k] + max(out[b,t-1,k], out[b,t-1,k-1])
// 32 batches x 8 column groups = 256 blocks, 1 wave each, 2 cols/lane.
//
// Round-7 theory: lgkmcnt completes DS ops IN ORDER. The round-5/6 row loop
// issued ds_read (prefetch) + ds_write (bsc) + shfl every row, so waiting
// for the previous row's shfl forced completion of the ds_read issued one
// row earlier — the 8-row prefetch slack was destroyed and every row
// exposed ~120cy+ of DS latency (measured ~290cy/row, VALUBusy 3%,
// invariant under sched_barrier removal in round 6).
// Fix: (1) all 32 ds_read_b64 for the tile are issued UPFRONT (tile data
// lives in 64 VGPRs; one sched_barrier keeps them there), so during the
// rows the DS queue holds ONLY the per-row shfl_up — it gets a full row
// to complete, and the recurrence cycle is shfl + 4 VALU per 2 rows.
// (2) boundary publish no longer touches LDS: lane 63 packs n1 pairs and
// issues one 8B agent-scope store per 2 rows straight to bws (covered by
// the tile-end vmcnt(0) drain).
// LDS staging via global_load_lds, lag-2 flag protocol, drain-then-publish
// are unchanged from the verified 303us kernel.

#define BB 32
#define TT 2048
#define KK 1024
#define GG 8
#define WW (KK / GG)      // 128 cols per group
#define RR 32             // rows per tile (flag granularity)
#define NT (TT / RR)      // 64 tiles

typedef __attribute__((address_space(1))) void GV;  // global
typedef __attribute__((address_space(3))) void LV;  // LDS

__global__ __launch_bounds__(64, 1)
void harddtw_td(const float* __restrict__ x, float* __restrict__ out,
                int* __restrict__ flags, float* __restrict__ bws)
{
    const int bid  = blockIdx.x;
    const int g    = bid >> 5;   // column group 0..7
    const int b    = bid & 31;   // batch
    const int lane = threadIdx.x;
    const bool lz  = (lane == 0);

    const int k0 = g * WW;
    const int kc = k0 + (lane << 1);
    const size_t base = (size_t)b * TT * KK;

    float* ol = out + base + kc;               // out cursor (row 0)

    int* myflag = flags + bid;
    int* upflag = flags + bid - 32;            // same batch, group g-1
    float*       mybw = bws + ((size_t)(b * GG + g)) * TT;       // we publish
    const float* upbw = bws + ((size_t)(b * GG + g - 1)) * TT;   // we consume

    __shared__ float lds[2][RR * WW];          // 2 x 16KB x-tile buffers

    // Staging: inst i stages rows 2i,2i+1 (1KB linear LDS; dest is
    // wave-uniform base + lane*16). Lane l covers row 2i+(l>>5),
    // float cols [4*(l&31), +4).
    const float* xstage = x + base + k0 + (size_t)(lane >> 5) * KK
                          + ((lane & 31) << 2);

    // Stage tile 0 into buffer 0 (latency overlaps the flag wait below).
    {
        const float* gp = xstage;
#pragma unroll
        for (int i = 0; i < RR / 2; ++i) {
            __builtin_amdgcn_global_load_lds((GV*)(void*)gp,
                                             (LV*)(void*)&lds[0][i * 256],
                                             16, 0, 0);
            gp += 2 * KK;
        }
    }

    float pv0 = 0.0f, pv1 = 0.0f;              // prev-row values (0 => row0 = x)
    float sh_prev = 0.0f;                      // left-neighbor pv1 from "row -1"
    float bcur = -INFINITY, bnxt = -INFINITY;  // boundary, lane j = row j-1 of tile

    if (g > 0) {
        while (__hip_atomic_load(upflag, __ATOMIC_RELAXED,
                                 __HIP_MEMORY_SCOPE_AGENT) < 1)
            __builtin_amdgcn_s_sleep(1);
        __asm__ volatile("" ::: "memory");
        if (lane == 0) {
            bcur = 0.0f;                       // row -1 virtual: max(0,0)
        } else if (lane < RR) {
            bcur = __hip_atomic_load(upbw + lane - 1, __ATOMIC_RELAXED,
                                     __HIP_MEMORY_SCOPE_AGENT);
        }
    }

    __asm__ volatile("s_waitcnt vmcnt(0)" ::: "memory");  // tile 0 staged

    int buf = 0;

#pragma unroll 1
    for (int r = 0; r < NT; ++r) {
        // Lag-2: producer must be 2 tiles ahead; then issue next tile's
        // boundary loads (coalesced 32 floats) so latency hides here.
        if (g > 0 && r < NT - 1) {
            while (__hip_atomic_load(upflag, __ATOMIC_RELAXED,
                                     __HIP_MEMORY_SCOPE_AGENT) < r + 2)
                __builtin_amdgcn_s_sleep(1);
            __asm__ volatile("" ::: "memory");
            if (lane < RR)
                bnxt = __hip_atomic_load(
                    upbw + (size_t)(r + 1) * RR + lane - 1,
                    __ATOMIC_RELAXED, __HIP_MEMORY_SCOPE_AGENT);
        }

        // Stage tile r+1 into the other buffer; completes by the tile-end
        // drain (one tile of slack).
        if (r < NT - 1) {
            const float* gp = xstage + (size_t)(r + 1) * RR * KK;
            float* lp = &lds[buf ^ 1][0];
#pragma unroll
            for (int i = 0; i < RR / 2; ++i) {
                __builtin_amdgcn_global_load_lds((GV*)(void*)gp,
                                                 (LV*)(void*)(lp + i * 256),
                                                 16, 0, 0);
                gp += 2 * KK;
            }
        }

        // --- Tile-wide batch read: all 32 rows into registers NOW, so the
        // row loop's DS queue contains ONLY the per-row shfl. ---
        float2 td[RR];
#pragma unroll
        for (int j = 0; j < RR; ++j)
            td[j] = *(const float2*)&lds[buf][j * WW + (lane << 1)];
        __builtin_amdgcn_sched_barrier(0);     // do not sink reads into rows

        const bool pub = (g < GG - 1);
        float bpair = 0.0f;                    // lane63 n1 of even row

#pragma unroll
        for (int j = 0; j < RR; ++j) {
            float2 xv = td[j];
            // Shfl-free chain first; issue this row's shfl ASAP.
            float n1 = xv.y + fmaxf(pv1, pv0);
            float sh_new = __shfl_up(n1, 1);   // consumed next row
            // Boundary broadcast: uniform readlane (VALU, no DS).
            float bv = __int_as_float(
                __builtin_amdgcn_readlane(__float_as_int(bcur), j));
            float left = lz ? bv : sh_prev;    // prev row's shfl, consumed late
            float n0 = xv.x + fmaxf(pv0, left);

            float2 o; o.x = n0; o.y = n1;
            *(float2*)ol = o;                  // plain store; never read x-block
            ol += KK;

            if ((j & 1) == 0) {
                bpair = n1;                    // stash even-row boundary val
            } else if (pub && lane == 63) {
                // One 8B agent-scope store per row pair, straight to bws.
                union { float f[2]; unsigned long long u; } cv;
                cv.f[0] = bpair; cv.f[1] = n1;
                __hip_atomic_store(
                    (unsigned long long*)(mybw + (size_t)r * RR + (j - 1)),
                    cv.u, __ATOMIC_RELAXED, __HIP_MEMORY_SCOPE_AGENT);
            }

            pv0 = n0; pv1 = n1; sh_prev = sh_new;
        }

        bcur = bnxt;

        // Release drain: boundary stores + out stores + next-tile staging.
        __asm__ volatile("s_waitcnt vmcnt(0)" ::: "memory");
        if (pub && lz)
            __hip_atomic_store(myflag, r + 1, __ATOMIC_RELAXED,
                               __HIP_MEMORY_SCOPE_AGENT);

        buf ^= 1;
    }
}

extern "C" void kernel_launch(void* const* d_in, const int* in_sizes, int n_in,
                              void* d_out, int out_size, void* d_ws, size_t ws_size,
                              hipStream_t stream) {
    (void)in_sizes; (void)n_in; (void)out_size; (void)ws_size;
    const float* x = (const float*)d_in[0];
    float* out = (float*)d_out;
    int* flags = (int*)d_ws;
    float* bws = (float*)((char*)d_ws + 4096);  // [BB][GG][TT] floats = 2MB

    // ws is re-poisoned to 0xAA before every timed launch; flags must be 0.
    // bws needs no init: every read is flag-gated behind its producer.
    hipMemsetAsync(flags, 0, BB * GG * sizeof(int), stream);

    harddtw_td<<<dim3(BB * GG), dim3(64), 0, stream>>>(x, out, flags, bws);
}

// Round 8
// 593.550 us; speedup vs baseline: 1.8269x; 1.0080x over previous
//
#include <hip/hip_runtime.h>
#include <math.h>

// Max-plus DP: out[b,t,k] = x[b,t,k] + max(out[b,t-1,k], out[b,t-1,k-1])
// 32 batches x 8 column groups = 256 blocks, 1 wave each, 2 cols/lane.
//
// Round-8 theory: T_tile ~ 9.1Kcy was invariant across all row-loop
// structures because every tile ended with s_waitcnt vmcnt(0) (full VMEM
// drain -> refill bubble = exposed HBM latency every tile) plus a blocking
// flag load. Effective single-wave BW 3.6B/cy/CU. Fix = T4: NEVER drain in
// the main loop. All waits become counted:
//   - boundary values of tile r-1 are packed in regs during tile r-1's rows
//     and stored as a PREFIX at tile r's top; publish(r-1) at tile r's end
//     waits vmcnt(48) (exact newer-op count 50), not 0.
//   - staging(r)-ready check at tile r top waits vmcnt(32) (exact 34-35).
//   - flag observation prefetched (fpre) post-rows, checked next tile;
//     spin only as fallback. bnxt issued post-rows so its auto-wait is
//     encodable (~34) and never a hidden drain.
// Out-row stores gate nothing (never read cross-block; flushed at kernel
// end). VMEM instruction counts audited per group role; asm memory seams
// pin code order so the counts hold.

#define BB 32
#define TT 2048
#define KK 1024
#define GG 8
#define WW (KK / GG)      // 128 cols per group
#define RR 32             // rows per tile (flag granularity)
#define NT (TT / RR)      // 64 tiles

typedef __attribute__((address_space(1))) void GV;  // global
typedef __attribute__((address_space(3))) void LV;  // LDS

__global__ __launch_bounds__(64, 1)
void harddtw_nd(const float* __restrict__ x, float* __restrict__ out,
                int* __restrict__ flags, float* __restrict__ bws)
{
    const int bid  = blockIdx.x;
    const int g    = bid >> 5;   // column group 0..7
    const int b    = bid & 31;   // batch
    const int lane = threadIdx.x;
    const bool lz  = (lane == 0);

    const int k0 = g * WW;
    const int kc = k0 + (lane << 1);
    const size_t base = (size_t)b * TT * KK;

    float* ol = out + base + kc;               // out cursor (row 0)

    int* myflag = flags + bid;
    int* upflag = flags + bid - 32;            // same batch, group g-1
    float*       mybw = bws + ((size_t)(b * GG + g)) * TT;       // we publish
    const float* upbw = bws + ((size_t)(b * GG + g - 1)) * TT;   // we consume

    __shared__ float lds[2][RR * WW];          // 2 x 16KB x-tile buffers

    // Staging: inst i stages rows 2i,2i+1 (1KB linear LDS). Lane l covers
    // row 2i+(l>>5), float cols [4*(l&31), +4).
    const float* xstage = x + base + k0 + (size_t)(lane >> 5) * KK
                          + ((lane & 31) << 2);

    // Stage tile 0 into buffer 0 (latency overlaps the init flag wait).
    {
        const float* gp = xstage;
#pragma unroll
        for (int i = 0; i < RR / 2; ++i) {
            __builtin_amdgcn_global_load_lds((GV*)(void*)gp,
                                             (LV*)(void*)&lds[0][i * 256],
                                             16, 0, 0);
            gp += 2 * KK;
        }
    }

    float pv0 = 0.0f, pv1 = 0.0f;              // prev-row values (0 => row0 = x)
    float sh_prev = 0.0f;                      // left-neighbor pv1 from "row -1"
    float bcur = -INFINITY, bnxt = -INFINITY;  // boundary, lane j = row j-1 of tile
    unsigned long long bp[16];                 // lane63: packed boundary pairs
#pragma unroll
    for (int i = 0; i < 16; ++i) bp[i] = 0ull;

    if (g > 0) {
        // Boundary for tile 0 needs producer tiles 0..0 => flag >= 1.
        while (__hip_atomic_load(upflag, __ATOMIC_RELAXED,
                                 __HIP_MEMORY_SCOPE_AGENT) < 1)
            __builtin_amdgcn_s_sleep(1);
        __asm__ volatile("" ::: "memory");
        if (lane == 0) {
            bcur = 0.0f;                       // row -1 virtual: max(0,0)
        } else if (lane < RR) {
            bcur = __hip_atomic_load(upbw + lane - 1, __ATOMIC_RELAXED,
                                     __HIP_MEMORY_SCOPE_AGENT);
        }
    }

    __asm__ volatile("s_waitcnt vmcnt(0)" ::: "memory");  // tile 0 staged
    int fpre = 0;                              // prefetched upflag value
    int buf = 0;

#pragma unroll 1
    for (int r = 0; r < NT; ++r) {
        const bool pub = (g < GG - 1);

        // [C] staging(r) ready: exact newer-op count 33-35 -> vmcnt(32).
        __asm__ volatile("s_waitcnt vmcnt(32)" ::: "memory");

        // [A] prefix: publish tile r-1's boundary values (packed last tile).
        if (pub && r > 0 && lane == 63) {
            unsigned long long* bwp =
                (unsigned long long*)(mybw + (size_t)(r - 1) * RR);
#pragma unroll
            for (int i = 0; i < 16; ++i)
                __hip_atomic_store(bwp + i, bp[i], __ATOMIC_RELAXED,
                                   __HIP_MEMORY_SCOPE_AGENT);
        }
        __asm__ volatile("" ::: "memory");     // pin A before B

        // [B] stage tile r+1 into the other buffer.
        if (r < NT - 1) {
            const float* gp = xstage + (size_t)(r + 1) * RR * KK;
            float* lp = &lds[buf ^ 1][0];
#pragma unroll
            for (int i = 0; i < RR / 2; ++i) {
                __builtin_amdgcn_global_load_lds((GV*)(void*)gp,
                                                 (LV*)(void*)(lp + i * 256),
                                                 16, 0, 0);
                gp += 2 * KK;
            }
        }
        __asm__ volatile("" ::: "memory");     // pin B before spin/rows

        // Flag check for next tile's boundary (value checked against the
        // prefetched fpre; spin only as fallback).
        if (g > 0 && r < NT - 1) {
            if (fpre < r + 2) {
                while (__hip_atomic_load(upflag, __ATOMIC_RELAXED,
                                         __HIP_MEMORY_SCOPE_AGENT) < r + 2)
                    __builtin_amdgcn_s_sleep(1);
            }
            __asm__ volatile("" ::: "memory");
        }

        // Tile-wide batch read: all 32 rows into registers; row loop's DS
        // queue then holds only the per-row shfl.
        float2 td[RR];
#pragma unroll
        for (int j = 0; j < RR; ++j)
            td[j] = *(const float2*)&lds[buf][j * WW + (lane << 1)];
        __builtin_amdgcn_sched_barrier(0);

        float bpe = 0.0f;                      // even-row boundary stash
#pragma unroll
        for (int j = 0; j < RR; ++j) {
            float2 xv = td[j];
            float n1 = xv.y + fmaxf(pv1, pv0);
            float sh_new = __shfl_up(n1, 1);   // consumed next row
            float bv = __int_as_float(
                __builtin_amdgcn_readlane(__float_as_int(bcur), j));
            float left = lz ? bv : sh_prev;
            float n0 = xv.x + fmaxf(pv0, left);

            float2 o; o.x = n0; o.y = n1;
            *(float2*)ol = o;                  // plain store; gates nothing
            ol += KK;

            if ((j & 1) == 0) {
                bpe = n1;
            } else {
                union { float f[2]; unsigned long long u; } cv;
                cv.f[0] = bpe; cv.f[1] = n1;
                bp[j >> 1] = cv.u;             // pack for next tile's [A]
            }

            pv0 = n0; pv1 = n1; sh_prev = sh_new;
        }
        __asm__ volatile("" ::: "memory");     // pin rows before BN/FP/W

        // [BN] boundary rows for tile r+1 (issued late: auto-wait at next
        // tile's first readlane is then encodable (~34), never a drain).
        if (g > 0 && r < NT - 1) {
            if (lane < RR)
                bnxt = __hip_atomic_load(
                    upbw + (size_t)(r + 1) * RR + lane - 1,
                    __ATOMIC_RELAXED, __HIP_MEMORY_SCOPE_AGENT);
            // [FP] prefetch flag value for next tile's check.
            if (r < NT - 2)
                fpre = __hip_atomic_load(upflag, __ATOMIC_RELAXED,
                                         __HIP_MEMORY_SCOPE_AGENT);
        }
        bcur = bnxt;
        __asm__ volatile("" ::: "memory");

        // [W] publish flag = r (tiles 0..r-1 readable). Needs only the [A]
        // prefix stores done: exact newer-op count 50 -> vmcnt(48).
        if (pub && r > 0) {
            __asm__ volatile("s_waitcnt vmcnt(48)" ::: "memory");
            if (lz)
                __hip_atomic_store(myflag, r, __ATOMIC_RELAXED,
                                   __HIP_MEMORY_SCOPE_AGENT);
        }

        buf ^= 1;
    }

    // Post-loop: publish the final tile's boundary + terminal flag = NT.
    if (g < GG - 1) {
        if (lane == 63) {
            unsigned long long* bwp =
                (unsigned long long*)(mybw + (size_t)(NT - 1) * RR);
#pragma unroll
            for (int i = 0; i < 16; ++i)
                __hip_atomic_store(bwp + i, bp[i], __ATOMIC_RELAXED,
                                   __HIP_MEMORY_SCOPE_AGENT);
        }
        __asm__ volatile("s_waitcnt vmcnt(0)" ::: "memory");
        if (lz)
            __hip_atomic_store(myflag, NT, __ATOMIC_RELAXED,
                               __HIP_MEMORY_SCOPE_AGENT);
    }
}

extern "C" void kernel_launch(void* const* d_in, const int* in_sizes, int n_in,
                              void* d_out, int out_size, void* d_ws, size_t ws_size,
                              hipStream_t stream) {
    (void)in_sizes; (void)n_in; (void)out_size; (void)ws_size;
    const float* x = (const float*)d_in[0];
    float* out = (float*)d_out;
    int* flags = (int*)d_ws;
    float* bws = (float*)((char*)d_ws + 4096);  // [BB][GG][TT] floats = 2MB

    // ws is re-poisoned to 0xAA before every timed launch; flags must be 0.
    // bws needs no init: every read is flag-gated behind its producer.
    hipMemsetAsync(flags, 0, BB * GG * sizeof(int), stream);

    harddtw_nd<<<dim3(BB * GG), dim3(64), 0, stream>>>(x, out, flags, bws);
}